// Round 2
// baseline (1017.382 us; speedup 1.0000x reference)
//
#include <hip/hip_runtime.h>

// HebbianConv2d: y = conv2d(x, w/||w||) + bias ; delta_w = cr @ unfold(x) - (sum cr)*w
// where r = softmax_o(y), cr = r^2 / sum_{b,h,w}(r)
//
// DTYPE-ROBUST build: a detector kernel sniffs whether inputs are fp32 or bf16
// (fp32 mantissa low-halves look like insane bf16 exponents); all work kernels
// are templated on FP32 and early-exit if the detected mode mismatches.
//
//   detect : write mode flag (0=bf16, 1=fp32) into ws
//   prep   : normalize weights (fp32, layout [k][o]), zero reducers
//   passA  : fp32 vector conv (4 positions/thread), writes y, r (fp32 -> ws rbuf),
//            reduces Sum r / Sum r^2 per channel
//   passB  : split-K MFMA 16x16x32_bf16: acc[32][144] += cr^T @ xpatch
//   fin    : delta = acc - (r2sum/rsum) * w, store

typedef unsigned short ushort_t;
typedef __attribute__((ext_vector_type(8))) short  short8v;
typedef __attribute__((ext_vector_type(4))) float  float4v;

#define BATCH 16
#define CIN   16
#define H     256
#define W     256
#define OCH   32
#define HO    254
#define WO    254
#define LPOS  (HO*WO)            // 64516
#define TOTPOS (BATCH*LPOS)      // 1032256
#define YELEMS (BATCH*OCH*LPOS)  // 33032192
#define KFEAT 144
#define NSUP  (BATCH*HO*2)       // 8128 row-half superchunks of 128 positions

// ws layout in floats
#define WS_WN   0        // 4608: wn[k*32+o] normalized weights fp32
#define WS_RSUM 4608     // 32
#define WS_R2   4640     // 32
#define WS_ACC  4672     // 4608: delta accumulator
#define WS_MODE 9280     // 1 int: 0=bf16 inputs, 1=fp32 inputs
#define WS_RBUF 9312     // TOTPOS*32: softmax r, [p][o] fp32 (128B aligned)

__device__ __forceinline__ float bf2f(ushort_t u){
  union{unsigned u; float f;} c; c.u = ((unsigned)u) << 16; return c.f;
}
__device__ __forceinline__ ushort_t f2bf(float f){
  union{float f; unsigned u;} c; c.f = f;
  unsigned x = c.u;
  return (ushort_t)((x + 0x7fffu + ((x >> 16) & 1u)) >> 16);   // RNE
}

__global__ __launch_bounds__(256) void hebb_detect(const ushort_t* __restrict__ x,
                                                   int* __restrict__ mode){
  // bf16 N(0,1): exponent field <= 0x81. fp32 storage: even ushorts are mantissa
  // low-halves (uniform) -> ~45% have exp >= 0x8C. Scan 16384 ushorts (32 KB).
  int tid = threadIdx.x;
  int bad = 0;
  for (int i = tid; i < 16384; i += 256){
    unsigned e = ((unsigned)x[i] >> 7) & 0xFFu;
    bad |= (e >= 0x8Cu) ? 1 : 0;
  }
  unsigned long long m = __ballot(bad);
  __shared__ unsigned long long sm[4];
  int wv = tid >> 6;
  if ((tid & 63) == 0) sm[wv] = m;
  __syncthreads();
  if (tid == 0) *mode = ((sm[0] | sm[1] | sm[2] | sm[3]) != 0ULL) ? 1 : 0;
}

__global__ __launch_bounds__(256) void hebb_prep(const ushort_t* __restrict__ w,
                                                 const int* __restrict__ mode,
                                                 float* __restrict__ ws){
  const int fp32 = *mode;
  const float* wf = (const float*)w;
  __shared__ float inv_s[OCH];
  int tid = threadIdx.x;
  if (tid < OCH){
    float s = 0.f;
    for (int k = 0; k < KFEAT; k++){
      float v = fp32 ? wf[tid*KFEAT + k] : bf2f(w[tid*KFEAT + k]);
      s += v*v;
    }
    float nrm = sqrtf(s);
    inv_s[tid] = (nrm == 0.f) ? 1.f : (1.f/nrm);
  }
  __syncthreads();
  for (int i = tid; i < 4608; i += 256){
    int k = i >> 5, o = i & 31;
    float v = fp32 ? wf[o*KFEAT + k] : bf2f(w[o*KFEAT + k]);
    ws[WS_WN + i] = v * inv_s[o];
    ws[WS_ACC + i] = 0.f;
  }
  if (tid < 64) ws[WS_RSUM + tid] = 0.f;
}

template<int FP32>
__global__ __launch_bounds__(256) void hebb_passA(
    const void* __restrict__ xv_, const void* __restrict__ bias_,
    const int* __restrict__ mode, const float* __restrict__ ws,
    float* __restrict__ rbuf, float* __restrict__ rsum_g,
    float* __restrict__ r2sum_g, void* __restrict__ yout_, int writeR){
  if (*mode != FP32) return;
  __shared__ float red_s[64];
  int tid = threadIdx.x;
  if (tid < 64) red_s[tid] = 0.f;
  __syncthreads();

  int gid = blockIdx.x*256 + tid;     // one group = 4 consecutive wo positions
  int row = gid >> 6;                 // b*HO + ho, 4064 rows, 64 groups/row
  int wo0 = (gid & 63) << 2;
  int b  = row / HO;
  int ho = row - b*HO;

  float acc[4][32];
  #pragma unroll
  for (int o = 0; o < 32; o++){
    float bv = FP32 ? ((const float*)bias_)[o] : bf2f(((const ushort_t*)bias_)[o]);
    #pragma unroll
    for (int u = 0; u < 4; u++) acc[u][o] = bv;
  }

  for (int c = 0; c < CIN; c++){
    #pragma unroll
    for (int i = 0; i < 3; i++){
      size_t off = (size_t)b*(CIN*H*W) + (size_t)(c*H + ho + i)*W + wo0;
      float xv[6];
      if (FP32){
        const float* xr = (const float*)xv_ + off;
        float4 a = *(const float4*)xr;                 // 16B aligned (wo0%4==0)
        float2 b2 = {0.f,0.f};
        if (wo0 < WO-2) b2 = *(const float2*)(xr + 4);
        xv[0]=a.x; xv[1]=a.y; xv[2]=a.z; xv[3]=a.w; xv[4]=b2.x; xv[5]=b2.y;
      } else {
        const ushort_t* xr = (const ushort_t*)xv_ + off;
        ushort4 x4 = *(const ushort4*)xr;              // 8B aligned
        ushort2 x2 = {0,0};
        if (wo0 < WO-2) x2 = *(const ushort2*)(xr + 4);
        xv[0]=bf2f(x4.x); xv[1]=bf2f(x4.y); xv[2]=bf2f(x4.z);
        xv[3]=bf2f(x4.w); xv[4]=bf2f(x2.x); xv[5]=bf2f(x2.y);
      }
      #pragma unroll
      for (int j = 0; j < 3; j++){
        int k = c*9 + i*3 + j;
        const float4* w4 = (const float4*)(ws + WS_WN + (k << 5)); // uniform address
        #pragma unroll
        for (int q = 0; q < 8; q++){
          float4 wv = w4[q];
          #pragma unroll
          for (int u = 0; u < 4; u++){
            float xu = xv[u + j];
            acc[u][4*q+0] += xu*wv.x;
            acc[u][4*q+1] += xu*wv.y;
            acc[u][4*q+2] += xu*wv.z;
            acc[u][4*q+3] += xu*wv.w;
          }
        }
      }
    }
  }

  // y writes before softmax overwrites acc
  size_t ybase = (size_t)b*(OCH*(size_t)LPOS) + (size_t)ho*WO + wo0;
  if (FP32){
    float* yf = (float*)yout_;
    if (wo0 <= WO-4){
      #pragma unroll
      for (int o = 0; o < 32; o++){
        size_t yi = ybase + (size_t)o*LPOS;
        float2 lo = {acc[0][o], acc[1][o]};
        float2 hi = {acc[2][o], acc[3][o]};
        *(float2*)(yf + yi)     = lo;   // yi even -> 8B aligned
        *(float2*)(yf + yi + 2) = hi;
      }
    } else {
      #pragma unroll
      for (int o = 0; o < 32; o++){
        size_t yi = ybase + (size_t)o*LPOS;
        yf[yi]   = acc[0][o];
        yf[yi+1] = acc[1][o];
      }
    }
  } else {
    ushort_t* yb = (ushort_t*)yout_;
    if (wo0 <= WO-4){
      #pragma unroll
      for (int o = 0; o < 32; o++){
        size_t yi = ybase + (size_t)o*LPOS;
        ushort2 lo = {f2bf(acc[0][o]), f2bf(acc[1][o])};
        ushort2 hi = {f2bf(acc[2][o]), f2bf(acc[3][o])};
        *(ushort2*)(yb + yi)     = lo;  // yi even -> 4B aligned
        *(ushort2*)(yb + yi + 2) = hi;
      }
    } else {
      #pragma unroll
      for (int o = 0; o < 32; o++){
        size_t yi = ybase + (size_t)o*LPOS;
        yb[yi]   = f2bf(acc[0][o]);
        yb[yi+1] = f2bf(acc[1][o]);
      }
    }
  }

  // softmax per position (in place: acc -> r)
  #pragma unroll
  for (int u = 0; u < 4; u++){
    float m = -3.0e38f;
    #pragma unroll
    for (int o = 0; o < 32; o++) m = fmaxf(m, acc[u][o]);
    float s = 0.f;
    #pragma unroll
    for (int o = 0; o < 32; o++){ float e = __expf(acc[u][o] - m); acc[u][o] = e; s += e; }
    float inv = 1.f/s;
    #pragma unroll
    for (int o = 0; o < 32; o++) acc[u][o] *= inv;
  }
  if (wo0 > WO-4){   // zero invalid positions so reductions are clean
    #pragma unroll
    for (int u = 2; u < 4; u++)
      #pragma unroll
      for (int o = 0; o < 32; o++) acc[u][o] = 0.f;
  }

  if (writeR){
    float* rp = rbuf + (size_t)(row*WO + wo0)*32;
    #pragma unroll
    for (int u = 0; u < 4; u++){
      if (wo0 + u < WO){
        #pragma unroll
        for (int o = 0; o < 32; o += 4){
          float4 t4 = {acc[u][o],acc[u][o+1],acc[u][o+2],acc[u][o+3]};
          *(float4*)(rp + u*32 + o) = t4;
        }
      }
    }
  }

  // reduce Sum r, Sum r^2 per channel
  int lane = tid & 63;
  #pragma unroll
  for (int o = 0; o < 32; o++){
    float v  = acc[0][o]+acc[1][o]+acc[2][o]+acc[3][o];
    float v2 = acc[0][o]*acc[0][o]+acc[1][o]*acc[1][o]
             + acc[2][o]*acc[2][o]+acc[3][o]*acc[3][o];
    #pragma unroll
    for (int off = 32; off > 0; off >>= 1){
      v  += __shfl_xor(v,  off, 64);
      v2 += __shfl_xor(v2, off, 64);
    }
    if (lane == 0){
      atomicAdd(&red_s[o],    v);
      atomicAdd(&red_s[32+o], v2);
    }
  }
  __syncthreads();
  if (tid < 32)      atomicAdd(rsum_g  + tid,      red_s[tid]);
  else if (tid < 64) atomicAdd(r2sum_g + (tid-32), red_s[tid]);
}

template<int FP32, int USE_RBUF>
__global__ __launch_bounds__(256) void hebb_passB(
    const void* __restrict__ xv_, const int* __restrict__ mode,
    const float* __restrict__ ws, const float* __restrict__ rbuf,
    const void* __restrict__ ybf_, float* __restrict__ acc_g){
  if (*mode != FP32) return;
  __shared__ __align__(16) ushort_t crs[32*128];    // [o][t] bf16, 8 KB
  __shared__ __align__(16) ushort_t xs[144*128];    // [khat][t] bf16, 36 KB
  __shared__ float rsinv_s[32];
  int tid = threadIdx.x;
  if (tid < 32){
    float rs = ws[WS_RSUM + tid];
    rsinv_s[tid] = (rs == 0.f) ? 1.f : (1.f/rs);
  }
  __syncthreads();

  float4v av[18];
  #pragma unroll
  for (int i = 0; i < 18; i++) av[i] = {0.f,0.f,0.f,0.f};
  int wave = tid >> 6, lane = tid & 63;
  int quad = lane >> 4, l16 = lane & 15;
  int t = tid & 127, kh0 = tid >> 7;   // wave-uniform kh0

  for (int s = blockIdx.x; s < NSUP; s += (int)gridDim.x){
    int row = s >> 1, half = s & 1;    // superchunk = 128 positions within one row
    int b = row / HO, ho = row - b*HO;
    int wo0 = half << 7;
    int tlen = half ? (WO - 128) : 128;   // 126 or 128
    size_t xoff = (size_t)b*(CIN*H*W) + (size_t)ho*W + wo0;
    bool tvalid = t < tlen;

    // stage xs[kh][t] (bf16); kh0 wave-uniform so offsets fold
    #pragma unroll
    for (int it = 0; it < 72; it++){
      const int kh = 2*it + kh0;
      const int c = kh/9, ij = kh - 9*c, ii = ij/3, jj = ij - 3*ii;
      size_t gi = xoff + (size_t)(c*H + ii)*W + jj + t;
      ushort_t val;
      if (FP32) val = tvalid ? f2bf(((const float*)xv_)[gi]) : (ushort_t)0;
      else      val = tvalid ? ((const ushort_t*)xv_)[gi]    : (ushort_t)0;
      xs[kh*128 + t] = val;
    }

    // stage crs[o][t] (threads 0..127, one position each)
    if (tid < 128){
      if (tvalid){
        float r[32];
        if (USE_RBUF){
          const float* rp = rbuf + (size_t)(row*WO + wo0 + tid)*32;
          #pragma unroll
          for (int o = 0; o < 32; o += 4){
            float4 v4 = *(const float4*)(rp + o);
            r[o]=v4.x; r[o+1]=v4.y; r[o+2]=v4.z; r[o+3]=v4.w;
          }
        } else {  // fallback: recompute softmax from stored y
          size_t yb = (size_t)b*(OCH*(size_t)LPOS) + (size_t)ho*WO + wo0 + tid;
          float m = -3.0e38f;
          #pragma unroll
          for (int o = 0; o < 32; o++){
            float v = FP32 ? ((const float*)ybf_)[yb + (size_t)o*LPOS]
                           : bf2f(((const ushort_t*)ybf_)[yb + (size_t)o*LPOS]);
            r[o] = v; m = fmaxf(m, v);
          }
          float ssum = 0.f;
          #pragma unroll
          for (int o = 0; o < 32; o++){ r[o] = __expf(r[o]-m); ssum += r[o]; }
          float inv = 1.f/ssum;
          #pragma unroll
          for (int o = 0; o < 32; o++) r[o] *= inv;
        }
        #pragma unroll
        for (int o = 0; o < 32; o++) crs[o*128 + tid] = f2bf(r[o]*r[o]*rsinv_s[o]);
      } else {
        #pragma unroll
        for (int o = 0; o < 32; o++) crs[o*128 + tid] = 0;
      }
    }
    __syncthreads();

    // each wave: one K=32 chunk; D[o][khat] tiles: 2 (M) x 9 (N)
    int t0 = wave*32;
    short8v a0 = *(const short8v*)(crs + l16*128      + t0 + quad*8);
    short8v a1 = *(const short8v*)(crs + (16+l16)*128 + t0 + quad*8);
    #pragma unroll
    for (int n = 0; n < 9; n++){
      short8v bfr = *(const short8v*)(xs + (n*16 + l16)*128 + t0 + quad*8);
      av[n]   = __builtin_amdgcn_mfma_f32_16x16x32_bf16(a0, bfr, av[n],   0,0,0);
      av[9+n] = __builtin_amdgcn_mfma_f32_16x16x32_bf16(a1, bfr, av[9+n], 0,0,0);
    }
    __syncthreads();
  }

  // flush: C/D layout col=lane&15 (khat), row=quad*4+reg (o)
  #pragma unroll
  for (int mi = 0; mi < 2; mi++){
    #pragma unroll
    for (int n = 0; n < 9; n++){
      #pragma unroll
      for (int rg = 0; rg < 4; rg++){
        int o  = mi*16 + quad*4 + rg;
        int kh = n*16 + l16;
        atomicAdd(acc_g + o*KFEAT + kh, av[mi*9+n][rg]);
      }
    }
  }
}

__global__ __launch_bounds__(256) void hebb_fin(const ushort_t* __restrict__ w,
    const int* __restrict__ mode, const float* __restrict__ ws,
    void* __restrict__ dout){
  int tid = blockIdx.x*256 + threadIdx.x;
  if (tid < 4608){
    const int fp32 = *mode;
    int o = tid / KFEAT;
    float rs = ws[WS_RSUM + o];
    rs = (rs == 0.f) ? 1.f : rs;
    float crsum = ws[WS_R2 + o] / rs;
    float wv = fp32 ? ((const float*)w)[tid] : bf2f(w[tid]);
    float d = ws[WS_ACC + tid] - crsum * wv;
    if (fp32) ((float*)dout)[(size_t)YELEMS + tid] = d;
    else      ((ushort_t*)dout)[(size_t)YELEMS + tid] = f2bf(d);
  }
}

extern "C" void kernel_launch(void* const* d_in, const int* in_sizes, int n_in,
                              void* d_out, int out_size, void* d_ws, size_t ws_size,
                              hipStream_t stream){
  const void* x    = d_in[0];
  const ushort_t* w = (const ushort_t*)d_in[1];
  const void* bias = d_in[2];
  float* ws   = (float*)d_ws;
  int*   mode = (int*)(ws + WS_MODE);
  float* rbuf = ws + WS_RBUF;
  size_t need = ((size_t)WS_RBUF + (size_t)TOTPOS*32) * sizeof(float);
  int use_rbuf = (ws_size >= need) ? 1 : 0;

  hebb_detect<<<1, 256, 0, stream>>>((const ushort_t*)x, mode);
  hebb_prep<<<1, 256, 0, stream>>>(w, mode, ws);
  hebb_passA<0><<<1016, 256, 0, stream>>>(x, bias, mode, ws, rbuf,
                                          ws + WS_RSUM, ws + WS_R2, d_out, use_rbuf);
  hebb_passA<1><<<1016, 256, 0, stream>>>(x, bias, mode, ws, rbuf,
                                          ws + WS_RSUM, ws + WS_R2, d_out, use_rbuf);
  if (use_rbuf){
    hebb_passB<0,1><<<512, 256, 0, stream>>>(x, mode, ws, rbuf, d_out, ws + WS_ACC);
    hebb_passB<1,1><<<512, 256, 0, stream>>>(x, mode, ws, rbuf, d_out, ws + WS_ACC);
  } else {
    hebb_passB<0,0><<<512, 256, 0, stream>>>(x, mode, ws, rbuf, d_out, ws + WS_ACC);
    hebb_passB<1,0><<<512, 256, 0, stream>>>(x, mode, ws, rbuf, d_out, ws + WS_ACC);
  }
  hebb_fin<<<18, 256, 0, stream>>>(w, mode, ws, d_out);
}

// Round 3
// 711.178 us; speedup vs baseline: 1.4306x; 1.4306x over previous
//
#include <hip/hip_runtime.h>

// HebbianConv2d: y = conv2d(x, w/||w||) + bias ; delta_w = cr @ unfold(x) - (sum cr)*w
// where r = softmax_o(y), cr = r^2 / sum_{b,h,w}(r)
//
// R2 -> R3: passB restructured. Old: LDS-staged superchunks + 9.4M atomicAdds
// (WRITE_SIZE showed 36.8 MB of atomic traffic; MfmaUtil 0.56%). New: passA
// writes sbuf[o][padded p] = bf16(r^2); passB reads A-fragments (contiguous
// 16B from sbuf) and B-fragments (8 fp32 from x, packed to bf16 via v_perm)
// straight from global, no LDS, no barriers, grid-stride over 32-pos chunks;
// each wave stores a private 4608-float partial slab; fin reduces slabs and
// divides by rsum.

typedef unsigned short ushort_t;
typedef __attribute__((ext_vector_type(8))) short  short8v;
typedef __attribute__((ext_vector_type(4))) float  float4v;

struct __attribute__((packed, aligned(4))) f4a { float x,y,z,w; };
struct __attribute__((packed, aligned(4))) f2a { float x,y; };
struct __attribute__((packed, aligned(2))) u2a { ushort_t x,y; };

#define BATCH 16
#define CIN   16
#define H     256
#define W     256
#define OCH   32
#define HO    254
#define WO    254
#define LPOS  (HO*WO)            // 64516
#define TOTPOS (BATCH*LPOS)      // 1032256
#define YELEMS (BATCH*OCH*LPOS)  // 33032192
#define KFEAT 144
#define NROWS (BATCH*HO)         // 4064
#define PADTOT (NROWS*256)       // 1040384 padded positions (row stride 256)
#define NCHUNK (NROWS*8)         // 32512 chunks of 32 padded positions
#define GRIDB 512
#define NSLAB (GRIDB*4)          // 2048 wave slabs

// ws layout in floats
#define WS_WN   0        // 4608: wn[k*32+o] normalized weights fp32
#define WS_RSUM 4608     // 32
#define WS_R2   4640     // 32
#define WS_ACC  4672     // 4608: fallback atomic accumulator
#define WS_MODE 9280     // 1 int: 0=bf16 inputs, 1=fp32 inputs
#define WS_PART 16384    // NSLAB*4608 floats = 9437184
#define WS_SBUF (16384 + 9437184)   // then PADTOT*32 ushorts (16646144 floats)
#define WS_NEED ((size_t)(WS_SBUF + PADTOT*16)*4)   // ~99.6 MB

__device__ __forceinline__ float bf2f(ushort_t u){
  union{unsigned u; float f;} c; c.u = ((unsigned)u) << 16; return c.f;
}
__device__ __forceinline__ ushort_t f2bf(float f){
  union{float f; unsigned u;} c; c.f = f;
  unsigned x = c.u;
  return (ushort_t)((x + 0x7fffu + ((x >> 16) & 1u)) >> 16);   // RNE
}
__device__ __forceinline__ unsigned as_u(float f){
  union{float f; unsigned u;} c; c.f = f; return c.u;
}

__global__ __launch_bounds__(256) void hebb_detect(const ushort_t* __restrict__ x,
                                                   int* __restrict__ mode){
  // bf16 N(0,1): exponent field <= 0x81. fp32 storage: even ushorts are mantissa
  // low-halves (uniform) -> ~45% have exp >= 0x8C. Scan 16384 ushorts (32 KB).
  int tid = threadIdx.x;
  int bad = 0;
  for (int i = tid; i < 16384; i += 256){
    unsigned e = ((unsigned)x[i] >> 7) & 0xFFu;
    bad |= (e >= 0x8Cu) ? 1 : 0;
  }
  unsigned long long m = __ballot(bad);
  __shared__ unsigned long long sm[4];
  int wv = tid >> 6;
  if ((tid & 63) == 0) sm[wv] = m;
  __syncthreads();
  if (tid == 0) *mode = ((sm[0] | sm[1] | sm[2] | sm[3]) != 0ULL) ? 1 : 0;
}

__global__ __launch_bounds__(256) void hebb_prep(const ushort_t* __restrict__ w,
                                                 const int* __restrict__ mode,
                                                 float* __restrict__ ws){
  const int fp32 = *mode;
  const float* wf = (const float*)w;
  __shared__ float inv_s[OCH];
  int tid = threadIdx.x;
  if (tid < OCH){
    float s = 0.f;
    for (int k = 0; k < KFEAT; k++){
      float v = fp32 ? wf[tid*KFEAT + k] : bf2f(w[tid*KFEAT + k]);
      s += v*v;
    }
    float nrm = sqrtf(s);
    inv_s[tid] = (nrm == 0.f) ? 1.f : (1.f/nrm);
  }
  __syncthreads();
  for (int i = tid; i < 4608; i += 256){
    int k = i >> 5, o = i & 31;
    float v = fp32 ? wf[o*KFEAT + k] : bf2f(w[o*KFEAT + k]);
    ws[WS_WN + i] = v * inv_s[o];
    ws[WS_ACC + i] = 0.f;
  }
  if (tid < 64) ws[WS_RSUM + tid] = 0.f;
}

template<int FP32>
__global__ __launch_bounds__(256) void hebb_passA(
    const void* __restrict__ xv_, const void* __restrict__ bias_,
    const int* __restrict__ mode, const float* __restrict__ ws,
    ushort_t* __restrict__ sbuf, float* __restrict__ rsum_g,
    float* __restrict__ r2sum_g, void* __restrict__ yout_, int writeR){
  if (*mode != FP32) return;
  __shared__ float red_s[64];
  int tid = threadIdx.x;
  if (tid < 64) red_s[tid] = 0.f;
  __syncthreads();

  int gid = blockIdx.x*256 + tid;     // one group = 4 consecutive wo positions
  int row = gid >> 6;                 // b*HO + ho, 4064 rows, 64 groups/row
  int wo0 = (gid & 63) << 2;
  int b  = row / HO;
  int ho = row - b*HO;

  float acc[4][32];
  #pragma unroll
  for (int o = 0; o < 32; o++){
    float bv = FP32 ? ((const float*)bias_)[o] : bf2f(((const ushort_t*)bias_)[o]);
    #pragma unroll
    for (int u = 0; u < 4; u++) acc[u][o] = bv;
  }

  for (int c = 0; c < CIN; c++){
    #pragma unroll
    for (int i = 0; i < 3; i++){
      size_t off = (size_t)b*(CIN*H*W) + (size_t)(c*H + ho + i)*W + wo0;
      float xv[6];
      if (FP32){
        const float* xr = (const float*)xv_ + off;
        float4 a = *(const float4*)xr;                 // 16B aligned (wo0%4==0)
        float2 b2 = {0.f,0.f};
        if (wo0 < WO-2) b2 = *(const float2*)(xr + 4);
        xv[0]=a.x; xv[1]=a.y; xv[2]=a.z; xv[3]=a.w; xv[4]=b2.x; xv[5]=b2.y;
      } else {
        const ushort_t* xr = (const ushort_t*)xv_ + off;
        ushort4 x4 = *(const ushort4*)xr;              // 8B aligned
        ushort2 x2 = {0,0};
        if (wo0 < WO-2) x2 = *(const ushort2*)(xr + 4);
        xv[0]=bf2f(x4.x); xv[1]=bf2f(x4.y); xv[2]=bf2f(x4.z);
        xv[3]=bf2f(x4.w); xv[4]=bf2f(x2.x); xv[5]=bf2f(x2.y);
      }
      #pragma unroll
      for (int j = 0; j < 3; j++){
        int k = c*9 + i*3 + j;
        const float4* w4 = (const float4*)(ws + WS_WN + (k << 5)); // uniform address
        #pragma unroll
        for (int q = 0; q < 8; q++){
          float4 wv = w4[q];
          #pragma unroll
          for (int u = 0; u < 4; u++){
            float xu = xv[u + j];
            acc[u][4*q+0] += xu*wv.x;
            acc[u][4*q+1] += xu*wv.y;
            acc[u][4*q+2] += xu*wv.z;
            acc[u][4*q+3] += xu*wv.w;
          }
        }
      }
    }
  }

  // y writes before softmax overwrites acc
  size_t ybase = (size_t)b*(OCH*(size_t)LPOS) + (size_t)ho*WO + wo0;
  if (FP32){
    float* yf = (float*)yout_;
    if (wo0 <= WO-4){
      #pragma unroll
      for (int o = 0; o < 32; o++){
        size_t yi = ybase + (size_t)o*LPOS;
        float2 lo = {acc[0][o], acc[1][o]};
        float2 hi = {acc[2][o], acc[3][o]};
        *(float2*)(yf + yi)     = lo;   // yi even -> 8B aligned
        *(float2*)(yf + yi + 2) = hi;
      }
    } else {
      #pragma unroll
      for (int o = 0; o < 32; o++){
        size_t yi = ybase + (size_t)o*LPOS;
        yf[yi]   = acc[0][o];
        yf[yi+1] = acc[1][o];
      }
    }
  } else {
    ushort_t* yb = (ushort_t*)yout_;
    if (wo0 <= WO-4){
      #pragma unroll
      for (int o = 0; o < 32; o++){
        size_t yi = ybase + (size_t)o*LPOS;
        ushort2 lo = {f2bf(acc[0][o]), f2bf(acc[1][o])};
        ushort2 hi = {f2bf(acc[2][o]), f2bf(acc[3][o])};
        *(ushort2*)(yb + yi)     = lo;
        *(ushort2*)(yb + yi + 2) = hi;
      }
    } else {
      #pragma unroll
      for (int o = 0; o < 32; o++){
        size_t yi = ybase + (size_t)o*LPOS;
        yb[yi]   = f2bf(acc[0][o]);
        yb[yi+1] = f2bf(acc[1][o]);
      }
    }
  }

  // softmax per position (in place: acc -> r)
  #pragma unroll
  for (int u = 0; u < 4; u++){
    float m = -3.0e38f;
    #pragma unroll
    for (int o = 0; o < 32; o++) m = fmaxf(m, acc[u][o]);
    float s = 0.f;
    #pragma unroll
    for (int o = 0; o < 32; o++){ float e = __expf(acc[u][o] - m); acc[u][o] = e; s += e; }
    float inv = 1.f/s;
    #pragma unroll
    for (int o = 0; o < 32; o++) acc[u][o] *= inv;
  }
  if (wo0 > WO-4){   // zero dead positions (wo 254,255) for reductions + sbuf pad
    #pragma unroll
    for (int u = 2; u < 4; u++)
      #pragma unroll
      for (int o = 0; o < 32; o++) acc[u][o] = 0.f;
  }

  if (writeR){
    // sbuf[o][row*256 + wo] = bf16(r^2); group wo0==252 also covers pads 254,255
    ushort_t* sp = sbuf + (size_t)row*256 + wo0;
    #pragma unroll
    for (int o = 0; o < 32; o++){
      ushort4 v;
      v.x = f2bf(acc[0][o]*acc[0][o]);
      v.y = f2bf(acc[1][o]*acc[1][o]);
      v.z = f2bf(acc[2][o]*acc[2][o]);
      v.w = f2bf(acc[3][o]*acc[3][o]);
      *(ushort4*)(sp + (size_t)o*PADTOT) = v;   // 8B aligned
    }
  }

  // reduce Sum r, Sum r^2 per channel
  int lane = tid & 63;
  #pragma unroll
  for (int o = 0; o < 32; o++){
    float v  = acc[0][o]+acc[1][o]+acc[2][o]+acc[3][o];
    float v2 = acc[0][o]*acc[0][o]+acc[1][o]*acc[1][o]
             + acc[2][o]*acc[2][o]+acc[3][o]*acc[3][o];
    #pragma unroll
    for (int off = 32; off > 0; off >>= 1){
      v  += __shfl_xor(v,  off, 64);
      v2 += __shfl_xor(v2, off, 64);
    }
    if (lane == 0){
      atomicAdd(&red_s[o],    v);
      atomicAdd(&red_s[32+o], v2);
    }
  }
  __syncthreads();
  if (tid < 32)      atomicAdd(rsum_g  + tid,      red_s[tid]);
  else if (tid < 64) atomicAdd(r2sum_g + (tid-32), red_s[tid]);
}

// Main passB: no LDS, no barriers, no atomics. Each wave grid-strides over
// 32-position chunks, accumulates full 32x144 in 72 VGPRs, writes a slab.
template<int FP32>
__global__ __launch_bounds__(256) void hebb_passB2(
    const void* __restrict__ xv_, const int* __restrict__ mode,
    const ushort_t* __restrict__ sbuf, float* __restrict__ partial){
  if (*mode != FP32) return;
  int tid = threadIdx.x, wave = tid >> 6, lane = tid & 63;
  int quad = lane >> 4, l16 = lane & 15;

  int koff[9];
  #pragma unroll
  for (int n = 0; n < 9; n++){
    int kh = n*16 + l16, c = kh/9, ij = kh - 9*c, ii = ij/3, jj = ij - 3*ii;
    koff[n] = (c*H + ii)*W + jj;
  }

  float4v av[18];
  #pragma unroll
  for (int i = 0; i < 18; i++) av[i] = (float4v){0.f,0.f,0.f,0.f};

  for (int cc0 = blockIdx.x*4 + wave; cc0 < NCHUNK; cc0 += GRIDB*4){
    int cc  = __builtin_amdgcn_readfirstlane(cc0);
    int row = cc >> 3, sub = cc & 7;
    int b = row / HO, ho = row - b*HO;
    int tail = (sub == 7);
    int xbase = b*(CIN*H*W) + ho*W + (sub << 5);
    int p0 = (row << 8) + (sub << 5);

    const ushort_t* sp = sbuf + (size_t)l16*PADTOT + p0 + quad*8;  // 16B aligned
    short8v a0 = *(const short8v*)sp;
    short8v a1 = *(const short8v*)(sp + (size_t)16*PADTOT);

    #pragma unroll
    for (int n = 0; n < 9; n++){
      short8v bv;
      if (FP32){
        const float* xp = (const float*)xv_ + (size_t)(xbase + koff[n] + quad*8);
        unsigned f[8];
        if (tail && quad == 3){     // wo 254,255 dead; avoid OOB cols
          f4a t0 = *(const f4a*)xp;
          f2a t1 = *(const f2a*)(xp + 4);
          f[0]=as_u(t0.x); f[1]=as_u(t0.y); f[2]=as_u(t0.z); f[3]=as_u(t0.w);
          f[4]=as_u(t1.x); f[5]=as_u(t1.y); f[6]=0u; f[7]=0u;
        } else {
          f4a t0 = *(const f4a*)xp;
          f4a t1 = *(const f4a*)(xp + 4);
          f[0]=as_u(t0.x); f[1]=as_u(t0.y); f[2]=as_u(t0.z); f[3]=as_u(t0.w);
          f[4]=as_u(t1.x); f[5]=as_u(t1.y); f[6]=as_u(t1.z); f[7]=as_u(t1.w);
        }
        union{unsigned u[4]; short8v v;} pk;
        pk.u[0] = __builtin_amdgcn_perm(f[1], f[0], 0x07060302u);  // trunc-to-bf16 pair
        pk.u[1] = __builtin_amdgcn_perm(f[3], f[2], 0x07060302u);
        pk.u[2] = __builtin_amdgcn_perm(f[5], f[4], 0x07060302u);
        pk.u[3] = __builtin_amdgcn_perm(f[7], f[6], 0x07060302u);
        bv = pk.v;
      } else {
        const ushort_t* xp = (const ushort_t*)xv_ + (size_t)(xbase + koff[n] + quad*8);
        union{ushort_t s[8]; short8v v;} pk;
        if (tail && quad == 3){
          u2a u0 = *(const u2a*)xp, u1 = *(const u2a*)(xp+2), u2 = *(const u2a*)(xp+4);
          pk.s[0]=u0.x; pk.s[1]=u0.y; pk.s[2]=u1.x; pk.s[3]=u1.y;
          pk.s[4]=u2.x; pk.s[5]=u2.y; pk.s[6]=0; pk.s[7]=0;
        } else {
          u2a u0 = *(const u2a*)xp,   u1 = *(const u2a*)(xp+2);
          u2a u2 = *(const u2a*)(xp+4), u3 = *(const u2a*)(xp+6);
          pk.s[0]=u0.x; pk.s[1]=u0.y; pk.s[2]=u1.x; pk.s[3]=u1.y;
          pk.s[4]=u2.x; pk.s[5]=u2.y; pk.s[6]=u3.x; pk.s[7]=u3.y;
        }
        bv = pk.v;
      }
      av[n]   = __builtin_amdgcn_mfma_f32_16x16x32_bf16(a0, bv, av[n],   0,0,0);
      av[9+n] = __builtin_amdgcn_mfma_f32_16x16x32_bf16(a1, bv, av[9+n], 0,0,0);
    }
  }

  // flush: each wave owns slab (blockIdx*4+wave); C/D: col=l16 (khat), row=quad*4+rg (o)
  float* myp = partial + (size_t)(blockIdx.x*4 + wave)*4608;
  #pragma unroll
  for (int mi = 0; mi < 2; mi++)
    #pragma unroll
    for (int n = 0; n < 9; n++)
      #pragma unroll
      for (int rg = 0; rg < 4; rg++){
        int o  = mi*16 + quad*4 + rg;
        int kh = n*16 + l16;
        myp[o*KFEAT + kh] = av[mi*9+n][rg];
      }
}

// Fallback (ws too small for sbuf/partials): old LDS-staged kernel, recomputes
// softmax from y, atomics into WS_ACC (cr pre-scaled by 1/rsum).
template<int FP32>
__global__ __launch_bounds__(256) void hebb_passB_fb(
    const void* __restrict__ xv_, const int* __restrict__ mode,
    const float* __restrict__ ws, const void* __restrict__ ybf_,
    float* __restrict__ acc_g){
  if (*mode != FP32) return;
  __shared__ __align__(16) ushort_t crs[32*128];
  __shared__ __align__(16) ushort_t xs[144*128];
  __shared__ float rsinv_s[32];
  int tid = threadIdx.x;
  if (tid < 32){
    float rs = ws[WS_RSUM + tid];
    rsinv_s[tid] = (rs == 0.f) ? 1.f : (1.f/rs);
  }
  __syncthreads();

  float4v av[18];
  #pragma unroll
  for (int i = 0; i < 18; i++) av[i] = (float4v){0.f,0.f,0.f,0.f};
  int wave = tid >> 6, lane = tid & 63;
  int quad = lane >> 4, l16 = lane & 15;
  int t = tid & 127, kh0 = tid >> 7;

  for (int s = blockIdx.x; s < NROWS*2; s += (int)gridDim.x){
    int row = s >> 1, half = s & 1;
    int b = row / HO, ho = row - b*HO;
    int wo0 = half << 7;
    int tlen = half ? (WO - 128) : 128;
    size_t xoff = (size_t)b*(CIN*H*W) + (size_t)ho*W + wo0;
    bool tvalid = t < tlen;

    #pragma unroll
    for (int it = 0; it < 72; it++){
      const int kh = 2*it + kh0;
      const int c = kh/9, ij = kh - 9*c, ii = ij/3, jj = ij - 3*ii;
      size_t gi = xoff + (size_t)(c*H + ii)*W + jj + t;
      ushort_t val;
      if (FP32) val = tvalid ? f2bf(((const float*)xv_)[gi]) : (ushort_t)0;
      else      val = tvalid ? ((const ushort_t*)xv_)[gi]    : (ushort_t)0;
      xs[kh*128 + t] = val;
    }
    if (tid < 128){
      if (tvalid){
        float r[32];
        size_t yb = (size_t)b*(OCH*(size_t)LPOS) + (size_t)ho*WO + wo0 + tid;
        float m = -3.0e38f;
        #pragma unroll
        for (int o = 0; o < 32; o++){
          float v = FP32 ? ((const float*)ybf_)[yb + (size_t)o*LPOS]
                         : bf2f(((const ushort_t*)ybf_)[yb + (size_t)o*LPOS]);
          r[o] = v; m = fmaxf(m, v);
        }
        float ssum = 0.f;
        #pragma unroll
        for (int o = 0; o < 32; o++){ r[o] = __expf(r[o]-m); ssum += r[o]; }
        float inv = 1.f/ssum;
        #pragma unroll
        for (int o = 0; o < 32; o++) r[o] *= inv;
        #pragma unroll
        for (int o = 0; o < 32; o++) crs[o*128 + tid] = f2bf(r[o]*r[o]*rsinv_s[o]);
      } else {
        #pragma unroll
        for (int o = 0; o < 32; o++) crs[o*128 + tid] = 0;
      }
    }
    __syncthreads();

    int t0 = wave*32;
    short8v a0 = *(const short8v*)(crs + l16*128      + t0 + quad*8);
    short8v a1 = *(const short8v*)(crs + (16+l16)*128 + t0 + quad*8);
    #pragma unroll
    for (int n = 0; n < 9; n++){
      short8v bfr = *(const short8v*)(xs + (n*16 + l16)*128 + t0 + quad*8);
      av[n]   = __builtin_amdgcn_mfma_f32_16x16x32_bf16(a0, bfr, av[n],   0,0,0);
      av[9+n] = __builtin_amdgcn_mfma_f32_16x16x32_bf16(a1, bfr, av[9+n], 0,0,0);
    }
    __syncthreads();
  }

  #pragma unroll
  for (int mi = 0; mi < 2; mi++)
    #pragma unroll
    for (int n = 0; n < 9; n++)
      #pragma unroll
      for (int rg = 0; rg < 4; rg++){
        int o  = mi*16 + quad*4 + rg;
        int kh = n*16 + l16;
        atomicAdd(acc_g + o*KFEAT + kh, av[mi*9+n][rg]);
      }
}

__global__ __launch_bounds__(256) void hebb_fin(const ushort_t* __restrict__ w,
    const int* __restrict__ mode, const float* __restrict__ ws,
    const float* __restrict__ partial, int use_rbuf, void* __restrict__ dout){
  int tid = blockIdx.x*256 + threadIdx.x;
  if (tid >= 4608) return;
  const int fp32 = *mode;
  int o = tid / KFEAT;
  float rs = ws[WS_RSUM + o];
  rs = (rs == 0.f) ? 1.f : rs;
  float base;
  if (use_rbuf){
    float s0=0.f, s1=0.f, s2=0.f, s3=0.f;
    for (int j = 0; j < NSLAB; j += 4){
      s0 += partial[(size_t)(j  )*4608 + tid];
      s1 += partial[(size_t)(j+1)*4608 + tid];
      s2 += partial[(size_t)(j+2)*4608 + tid];
      s3 += partial[(size_t)(j+3)*4608 + tid];
    }
    base = ((s0+s1)+(s2+s3)) / rs;
  } else {
    base = ws[WS_ACC + tid];   // fallback atomics (already /rsum)
  }
  float crsum = ws[WS_R2 + o] / rs;
  float wv = fp32 ? ((const float*)w)[tid] : bf2f(w[tid]);
  float d = base - crsum * wv;
  if (fp32) ((float*)dout)[(size_t)YELEMS + tid] = d;
  else      ((ushort_t*)dout)[(size_t)YELEMS + tid] = f2bf(d);
}

extern "C" void kernel_launch(void* const* d_in, const int* in_sizes, int n_in,
                              void* d_out, int out_size, void* d_ws, size_t ws_size,
                              hipStream_t stream){
  const void* x    = d_in[0];
  const ushort_t* w = (const ushort_t*)d_in[1];
  const void* bias = d_in[2];
  float* ws   = (float*)d_ws;
  int*   mode = (int*)(ws + WS_MODE);
  float* part = ws + WS_PART;
  ushort_t* sbuf = (ushort_t*)(ws + WS_SBUF);
  int use_rbuf = (ws_size >= WS_NEED) ? 1 : 0;

  hebb_detect<<<1, 256, 0, stream>>>((const ushort_t*)x, mode);
  hebb_prep<<<1, 256, 0, stream>>>(w, mode, ws);
  hebb_passA<0><<<1016, 256, 0, stream>>>(x, bias, mode, ws, sbuf,
                                          ws + WS_RSUM, ws + WS_R2, d_out, use_rbuf);
  hebb_passA<1><<<1016, 256, 0, stream>>>(x, bias, mode, ws, sbuf,
                                          ws + WS_RSUM, ws + WS_R2, d_out, use_rbuf);
  if (use_rbuf){
    hebb_passB2<0><<<GRIDB, 256, 0, stream>>>(x, mode, sbuf, part);
    hebb_passB2<1><<<GRIDB, 256, 0, stream>>>(x, mode, sbuf, part);
  } else {
    hebb_passB_fb<0><<<512, 256, 0, stream>>>(x, mode, ws, d_out, ws + WS_ACC);
    hebb_passB_fb<1><<<512, 256, 0, stream>>>(x, mode, ws, d_out, ws + WS_ACC);
  }
  hebb_fin<<<18, 256, 0, stream>>>(w, mode, ws, part, use_rbuf, d_out);
}

// Round 4
// 507.951 us; speedup vs baseline: 2.0029x; 1.4001x over previous
//
#include <hip/hip_runtime.h>

// HebbianConv2d: y = conv2d(x, w/||w||) + bias ; delta_w = cr @ unfold(x) - (sum cr)*w
// where r = softmax_o(y), cr = r^2 / sum_{b,h,w}(r)
//
// R3 -> R4: passA rewritten on MFMA. Old fp32 vector conv was latency-bound
// (335 us, VALUBusy 35%, occupancy 11%). New: conv as 9 shifted GEMMs over cin
// using mfma_f32_32x32x16_bf16; A = wn_ij (preloaded, wave-invariant), B = x
// slab loads (8 coalesced dwords/lane -> v_perm bf16 pack). Softmax across och
// = 16 local regs + shfl_xor(32). passB2 gains in-block LDS slab reduction
// (512 slabs, ws need 76 MB). fin reads 4x less.

typedef unsigned short ushort_t;
typedef __attribute__((ext_vector_type(8)))  short  short8v;
typedef __attribute__((ext_vector_type(4)))  float  float4v;
typedef __attribute__((ext_vector_type(16))) float  float16v;

struct __attribute__((packed, aligned(4))) f4a { float x,y,z,w; };
struct __attribute__((packed, aligned(4))) f2a { float x,y; };
struct __attribute__((packed, aligned(2))) u2a { ushort_t x,y; };

#define BATCH 16
#define CIN   16
#define H     256
#define W     256
#define HW    (H*W)
#define OCH   32
#define HO    254
#define WO    254
#define LPOS  (HO*WO)            // 64516
#define TOTPOS (BATCH*LPOS)      // 1032256
#define YELEMS (BATCH*OCH*LPOS)  // 33032192
#define KFEAT 144
#define NROWS (BATCH*HO)         // 4064
#define PADTOT (NROWS*256)       // 1040384 padded positions (row stride 256)
#define NCHUNK (NROWS*8)         // 32512 chunks of 32 padded positions
#define GRIDA 1016               // passA blocks: 1016*4 waves * 8 chunks = 32512 exact
#define GRIDB 512                // passB blocks
#define NSLAB GRIDB              // one slab per block (LDS-reduced)

// ws layout in floats
#define WS_RSUM 0        // 32
#define WS_R2   32       // 32
#define WS_ACC  64       // 4608: fallback atomic accumulator
#define WS_MODE 4672     // 1 int: 0=bf16 inputs, 1=fp32 inputs
#define WS_WNB  4680     // 4608 ushorts (2304 floats): wnb[ij][c][och] bf16
#define WS_PART 8192     // NSLAB*4608 floats = 2359296
#define WS_SBUF (8192 + 2359296)          // PADTOT*32 ushorts = 16646144 floats
#define WS_NEED ((size_t)(WS_SBUF + 16646144)*4)   // ~76.1 MB

__device__ __forceinline__ float bf2f(ushort_t u){
  union{unsigned u; float f;} c; c.u = ((unsigned)u) << 16; return c.f;
}
__device__ __forceinline__ ushort_t f2bf(float f){
  union{float f; unsigned u;} c; c.f = f;
  unsigned x = c.u;
  return (ushort_t)((x + 0x7fffu + ((x >> 16) & 1u)) >> 16);   // RNE
}
__device__ __forceinline__ unsigned as_u(float f){
  union{float f; unsigned u;} c; c.f = f; return c.u;
}

__global__ __launch_bounds__(256) void hebb_detect(const ushort_t* __restrict__ x,
                                                   int* __restrict__ mode){
  // bf16 N(0,1): exponent field <= 0x81. fp32 storage: even ushorts are mantissa
  // low-halves (uniform) -> ~45% have exp >= 0x8C. Scan 16384 ushorts (32 KB).
  int tid = threadIdx.x;
  int bad = 0;
  for (int i = tid; i < 16384; i += 256){
    unsigned e = ((unsigned)x[i] >> 7) & 0xFFu;
    bad |= (e >= 0x8Cu) ? 1 : 0;
  }
  unsigned long long m = __ballot(bad);
  __shared__ unsigned long long sm[4];
  int wv = tid >> 6;
  if ((tid & 63) == 0) sm[wv] = m;
  __syncthreads();
  if (tid == 0) *mode = ((sm[0] | sm[1] | sm[2] | sm[3]) != 0ULL) ? 1 : 0;
}

__global__ __launch_bounds__(256) void hebb_prep(const ushort_t* __restrict__ w,
                                                 const int* __restrict__ mode,
                                                 float* __restrict__ ws){
  const int fp32 = *mode;
  const float* wf = (const float*)w;
  __shared__ float inv_s[OCH];
  int tid = threadIdx.x;
  if (tid < OCH){
    float s = 0.f;
    for (int k = 0; k < KFEAT; k++){
      float v = fp32 ? wf[tid*KFEAT + k] : bf2f(w[tid*KFEAT + k]);
      s += v*v;
    }
    float nrm = sqrtf(s);
    inv_s[tid] = (nrm == 0.f) ? 1.f : (1.f/nrm);
  }
  __syncthreads();
  ushort_t* wnb = (ushort_t*)(ws + WS_WNB);
  for (int i = tid; i < 4608; i += 256){
    // i = (ij*16 + c)*32 + o ; k_full = c*9 + ij
    int o = i & 31, rest = i >> 5;
    int ij = rest >> 4, c = rest & 15;
    int k = c*9 + ij;
    float v = fp32 ? wf[o*KFEAT + k] : bf2f(w[o*KFEAT + k]);
    wnb[i] = f2bf(v * inv_s[o]);
    ws[WS_ACC + i] = 0.f;
  }
  if (tid < 64) ws[WS_RSUM + tid] = 0.f;
}

// MFMA conv + softmax + reductions + sbuf(r^2) + y.
template<int FP32>
__global__ __launch_bounds__(256) void hebb_passA2(
    const void* __restrict__ xv_, const void* __restrict__ bias_,
    const int* __restrict__ mode, const float* __restrict__ ws,
    ushort_t* __restrict__ sbuf, float* __restrict__ rsum_g,
    float* __restrict__ r2sum_g, void* __restrict__ yout_, int writeS){
  if (*mode != FP32) return;
  __shared__ float red_s[64];
  int tid = threadIdx.x;
  if (tid < 64) red_s[tid] = 0.f;
  __syncthreads();
  int wave = tid >> 6, lane = tid & 63;
  int pos = lane & 31, half = lane >> 5;

  // A-fragments: wnb[ij][c][och]; lane: m=och=pos-index? no: m = lane&31, k = half*8+i
  const ushort_t* wnb = (const ushort_t*)(ws + WS_WNB);
  short8v wa[9];
  #pragma unroll
  for (int ij = 0; ij < 9; ij++){
    union{ushort_t s[8]; short8v v;} pk;
    #pragma unroll
    for (int i = 0; i < 8; i++)
      pk.s[i] = wnb[(ij*16 + half*8 + i)*32 + pos];   // och = lane&31 = pos
    wa[ij] = pk.v;
  }
  // bias per C-reg row: och_r = (r&3)+8*(r>>2)+4*half
  float bv[16];
  #pragma unroll
  for (int r = 0; r < 16; r++){
    int och = (r&3) + 8*(r>>2) + 4*half;
    bv[r] = FP32 ? ((const float*)bias_)[och] : bf2f(((const ushort_t*)bias_)[och]);
  }
  float rsA[16], r2A[16];
  #pragma unroll
  for (int r = 0; r < 16; r++){ rsA[r] = 0.f; r2A[r] = 0.f; }

  for (int cc0 = blockIdx.x*4 + wave; cc0 < NCHUNK; cc0 += GRIDA*4){
    int cc = __builtin_amdgcn_readfirstlane(cc0);
    int row = cc >> 3, sub = cc & 7;
    int b = row / HO, ho = row - b*HO;
    int wo0 = sub << 5;
    int wo = wo0 + pos;                 // 254,255 dead on sub==7

    float16v av;
    #pragma unroll
    for (int r = 0; r < 16; r++) av[r] = bv[r];   // C init = bias

    #pragma unroll
    for (int ij = 0; ij < 9; ij++){
      const int ii = ij/3, jj = ij - 3*ii;
      int wcol = wo + jj; wcol = (wcol < 256) ? wcol : 255;   // clamp: no OOB
      size_t a0 = (size_t)b*(CIN*HW) + (size_t)(half*8)*HW + (size_t)(ho+ii)*W + wcol;
      short8v bx;
      if (FP32){
        const float* xp = (const float*)xv_;
        unsigned g[8];
        #pragma unroll
        for (int i2 = 0; i2 < 8; i2++)
          g[i2] = as_u(xp[a0 + (size_t)i2*HW]) + 0x8000u;  // round-half-up to bf16
        union{unsigned u[4]; short8v v;} pk;
        pk.u[0] = __builtin_amdgcn_perm(g[1], g[0], 0x07060302u);
        pk.u[1] = __builtin_amdgcn_perm(g[3], g[2], 0x07060302u);
        pk.u[2] = __builtin_amdgcn_perm(g[5], g[4], 0x07060302u);
        pk.u[3] = __builtin_amdgcn_perm(g[7], g[6], 0x07060302u);
        bx = pk.v;
      } else {
        const ushort_t* xp = (const ushort_t*)xv_;
        union{ushort_t s[8]; short8v v;} pk;
        #pragma unroll
        for (int i2 = 0; i2 < 8; i2++)
          pk.s[i2] = xp[a0 + (size_t)i2*HW];
        bx = pk.v;
      }
      av = __builtin_amdgcn_mfma_f32_32x32x16_bf16(wa[ij], bx, av, 0, 0, 0);
    }

    // y store (C/D: col=lane&31=pos, row=(r&3)+8*(r>>2)+4*half=och)
    int valid = (wo < WO) ? 1 : 0;
    if (valid){
      size_t yb = (size_t)b*(OCH*(size_t)LPOS) + (size_t)(half*4)*LPOS
                + (size_t)ho*WO + wo;
      #pragma unroll
      for (int r = 0; r < 16; r++){
        size_t yi = yb + (size_t)(((r&3) + 8*(r>>2)))*LPOS;
        if (FP32) ((float*)yout_)[yi] = av[r];
        else      ((ushort_t*)yout_)[yi] = f2bf(av[r]);
      }
    }

    // softmax over och (16 local + partner half via shfl_xor 32)
    float m = -3.0e38f;
    #pragma unroll
    for (int r = 0; r < 16; r++) m = fmaxf(m, av[r]);
    m = fmaxf(m, __shfl_xor(m, 32));
    float s = 0.f;
    #pragma unroll
    for (int r = 0; r < 16; r++){ float e = __expf(av[r] - m); av[r] = e; s += e; }
    s += __shfl_xor(s, 32);
    float inv = valid ? (1.f/s) : 0.f;

    ushort_t* sp = sbuf + (size_t)row*256 + wo0 + pos;
    #pragma unroll
    for (int r = 0; r < 16; r++){
      float rr = av[r]*inv;              // r (0 for dead pos -> clean pads)
      float r2 = rr*rr;
      rsA[r] += rr; r2A[r] += r2;
      if (writeS){
        int och = (r&3) + 8*(r>>2) + 4*half;
        sp[(size_t)och*PADTOT] = f2bf(r2);
      }
    }
  }

  // reduce Sum r, Sum r^2 per channel (butterfly within each 32-half)
  #pragma unroll
  for (int r = 0; r < 16; r++){
    float a = rsA[r], b2 = r2A[r];
    #pragma unroll
    for (int off = 1; off < 32; off <<= 1){
      a  += __shfl_xor(a,  off);
      b2 += __shfl_xor(b2, off);
    }
    if (pos == 0){                       // lanes 0 and 32
      int och = (r&3) + 8*(r>>2) + 4*half;
      atomicAdd(&red_s[och],      a);
      atomicAdd(&red_s[32 + och], b2);
    }
  }
  __syncthreads();
  if (tid < 32)      atomicAdd(rsum_g  + tid,      red_s[tid]);
  else if (tid < 64) atomicAdd(r2sum_g + (tid-32), red_s[tid]);
}

// passB: no barriers in main loop; grid-stride over 32-pos chunks; 16x16x32 MFMA
// contracting positions; in-block LDS reduction -> one slab per block.
template<int FP32>
__global__ __launch_bounds__(256) void hebb_passB2(
    const void* __restrict__ xv_, const int* __restrict__ mode,
    const ushort_t* __restrict__ sbuf, float* __restrict__ partial){
  if (*mode != FP32) return;
  __shared__ float redp[4608];
  int tid = threadIdx.x, wave = tid >> 6, lane = tid & 63;
  int quad = lane >> 4, l16 = lane & 15;

  int koff[9];
  #pragma unroll
  for (int n = 0; n < 9; n++){
    int kh = n*16 + l16, c = kh/9, ij = kh - 9*c, ii = ij/3, jj = ij - 3*ii;
    koff[n] = (c*H + ii)*W + jj;
  }

  float4v av[18];
  #pragma unroll
  for (int i = 0; i < 18; i++) av[i] = (float4v){0.f,0.f,0.f,0.f};

  for (int cc0 = blockIdx.x*4 + wave; cc0 < NCHUNK; cc0 += GRIDB*4){
    int cc  = __builtin_amdgcn_readfirstlane(cc0);
    int row = cc >> 3, sub = cc & 7;
    int b = row / HO, ho = row - b*HO;
    int tail = (sub == 7);
    int xbase = b*(CIN*HW) + ho*W + (sub << 5);
    int p0 = (row << 8) + (sub << 5);

    const ushort_t* sp = sbuf + (size_t)l16*PADTOT + p0 + quad*8;  // 16B aligned
    short8v a0 = *(const short8v*)sp;
    short8v a1 = *(const short8v*)(sp + (size_t)16*PADTOT);

    #pragma unroll
    for (int n = 0; n < 9; n++){
      short8v bv;
      if (FP32){
        const float* xp = (const float*)xv_ + (size_t)(xbase + koff[n] + quad*8);
        unsigned f[8];
        if (tail && quad == 3){     // wo 254,255 dead; avoid OOB cols
          f4a t0 = *(const f4a*)xp;
          f2a t1 = *(const f2a*)(xp + 4);
          f[0]=as_u(t0.x); f[1]=as_u(t0.y); f[2]=as_u(t0.z); f[3]=as_u(t0.w);
          f[4]=as_u(t1.x); f[5]=as_u(t1.y); f[6]=0u; f[7]=0u;
        } else {
          f4a t0 = *(const f4a*)xp;
          f4a t1 = *(const f4a*)(xp + 4);
          f[0]=as_u(t0.x); f[1]=as_u(t0.y); f[2]=as_u(t0.z); f[3]=as_u(t0.w);
          f[4]=as_u(t1.x); f[5]=as_u(t1.y); f[6]=as_u(t1.z); f[7]=as_u(t1.w);
        }
        union{unsigned u[4]; short8v v;} pk;
        pk.u[0] = __builtin_amdgcn_perm(f[1], f[0], 0x07060302u);  // trunc bf16
        pk.u[1] = __builtin_amdgcn_perm(f[3], f[2], 0x07060302u);
        pk.u[2] = __builtin_amdgcn_perm(f[5], f[4], 0x07060302u);
        pk.u[3] = __builtin_amdgcn_perm(f[7], f[6], 0x07060302u);
        bv = pk.v;
      } else {
        const ushort_t* xp = (const ushort_t*)xv_ + (size_t)(xbase + koff[n] + quad*8);
        union{ushort_t s[8]; short8v v;} pk;
        if (tail && quad == 3){
          u2a u0 = *(const u2a*)xp, u1 = *(const u2a*)(xp+2), u2 = *(const u2a*)(xp+4);
          pk.s[0]=u0.x; pk.s[1]=u0.y; pk.s[2]=u1.x; pk.s[3]=u1.y;
          pk.s[4]=u2.x; pk.s[5]=u2.y; pk.s[6]=0; pk.s[7]=0;
        } else {
          u2a u0 = *(const u2a*)xp,   u1 = *(const u2a*)(xp+2);
          u2a u2 = *(const u2a*)(xp+4), u3 = *(const u2a*)(xp+6);
          pk.s[0]=u0.x; pk.s[1]=u0.y; pk.s[2]=u1.x; pk.s[3]=u1.y;
          pk.s[4]=u2.x; pk.s[5]=u2.y; pk.s[6]=u3.x; pk.s[7]=u3.y;
        }
        bv = pk.v;
      }
      av[n]   = __builtin_amdgcn_mfma_f32_16x16x32_bf16(a0, bv, av[n],   0,0,0);
      av[9+n] = __builtin_amdgcn_mfma_f32_16x16x32_bf16(a1, bv, av[9+n], 0,0,0);
    }
  }

  // cross-wave LDS reduce (C/D: col=l16=khat, row=quad*4+rg=o)
  for (int wv = 0; wv < 4; wv++){
    if (wave == wv){
      #pragma unroll
      for (int mi = 0; mi < 2; mi++)
        #pragma unroll
        for (int n = 0; n < 9; n++)
          #pragma unroll
          for (int rg = 0; rg < 4; rg++){
            int o  = mi*16 + quad*4 + rg;
            int kh = n*16 + l16;
            if (wv == 0) redp[o*KFEAT + kh]  = av[mi*9+n][rg];
            else         redp[o*KFEAT + kh] += av[mi*9+n][rg];
          }
    }
    __syncthreads();
  }
  float* myp = partial + (size_t)blockIdx.x*4608;
  for (int i = tid; i < 4608; i += 256) myp[i] = redp[i];
}

// Fallback (ws too small for sbuf/partials): LDS-staged, recomputes softmax
// from y, atomics into WS_ACC (cr pre-scaled by 1/rsum).
template<int FP32>
__global__ __launch_bounds__(256) void hebb_passB_fb(
    const void* __restrict__ xv_, const int* __restrict__ mode,
    const float* __restrict__ ws, const void* __restrict__ ybf_,
    float* __restrict__ acc_g){
  if (*mode != FP32) return;
  __shared__ __align__(16) ushort_t crs[32*128];
  __shared__ __align__(16) ushort_t xs[144*128];
  __shared__ float rsinv_s[32];
  int tid = threadIdx.x;
  if (tid < 32){
    float rs = ws[WS_RSUM + tid];
    rsinv_s[tid] = (rs == 0.f) ? 1.f : (1.f/rs);
  }
  __syncthreads();

  float4v av[18];
  #pragma unroll
  for (int i = 0; i < 18; i++) av[i] = (float4v){0.f,0.f,0.f,0.f};
  int wave = tid >> 6, lane = tid & 63;
  int quad = lane >> 4, l16 = lane & 15;
  int t = tid & 127, kh0 = tid >> 7;

  for (int s = blockIdx.x; s < NROWS*2; s += (int)gridDim.x){
    int row = s >> 1, half = s & 1;
    int b = row / HO, ho = row - b*HO;
    int wo0 = half << 7;
    int tlen = half ? (WO - 128) : 128;
    size_t xoff = (size_t)b*(CIN*HW) + (size_t)ho*W + wo0;
    bool tvalid = t < tlen;

    #pragma unroll
    for (int it = 0; it < 72; it++){
      const int kh = 2*it + kh0;
      const int c = kh/9, ij = kh - 9*c, ii = ij/3, jj = ij - 3*ii;
      size_t gi = xoff + (size_t)(c*H + ii)*W + jj + t;
      ushort_t val;
      if (FP32) val = tvalid ? f2bf(((const float*)xv_)[gi]) : (ushort_t)0;
      else      val = tvalid ? ((const ushort_t*)xv_)[gi]    : (ushort_t)0;
      xs[kh*128 + t] = val;
    }
    if (tid < 128){
      if (tvalid){
        float r[32];
        size_t yb = (size_t)b*(OCH*(size_t)LPOS) + (size_t)ho*WO + wo0 + tid;
        float m = -3.0e38f;
        #pragma unroll
        for (int o = 0; o < 32; o++){
          float v = FP32 ? ((const float*)ybf_)[yb + (size_t)o*LPOS]
                         : bf2f(((const ushort_t*)ybf_)[yb + (size_t)o*LPOS]);
          r[o] = v; m = fmaxf(m, v);
        }
        float ssum = 0.f;
        #pragma unroll
        for (int o = 0; o < 32; o++){ r[o] = __expf(r[o]-m); ssum += r[o]; }
        float inv = 1.f/ssum;
        #pragma unroll
        for (int o = 0; o < 32; o++) r[o] *= inv;
        #pragma unroll
        for (int o = 0; o < 32; o++) crs[o*128 + tid] = f2bf(r[o]*r[o]*rsinv_s[o]);
      } else {
        #pragma unroll
        for (int o = 0; o < 32; o++) crs[o*128 + tid] = 0;
      }
    }
    __syncthreads();

    int t0 = wave*32;
    short8v a0 = *(const short8v*)(crs + l16*128      + t0 + quad*8);
    short8v a1 = *(const short8v*)(crs + (16+l16)*128 + t0 + quad*8);
    #pragma unroll
    for (int n = 0; n < 9; n++){
      short8v bfr = *(const short8v*)(xs + (n*16 + l16)*128 + t0 + quad*8);
      av[n]   = __builtin_amdgcn_mfma_f32_16x16x32_bf16(a0, bfr, av[n],   0,0,0);
      av[9+n] = __builtin_amdgcn_mfma_f32_16x16x32_bf16(a1, bfr, av[9+n], 0,0,0);
    }
    __syncthreads();
  }

  #pragma unroll
  for (int mi = 0; mi < 2; mi++)
    #pragma unroll
    for (int n = 0; n < 9; n++)
      #pragma unroll
      for (int rg = 0; rg < 4; rg++){
        int o  = mi*16 + quad*4 + rg;
        int kh = n*16 + l16;
        atomicAdd(acc_g + o*KFEAT + kh, av[mi*9+n][rg]);
      }
}

__global__ __launch_bounds__(256) void hebb_fin(const ushort_t* __restrict__ w,
    const int* __restrict__ mode, const float* __restrict__ ws,
    const float* __restrict__ partial, int use_rbuf, void* __restrict__ dout){
  int tid = blockIdx.x*256 + threadIdx.x;
  if (tid >= 4608) return;
  const int fp32 = *mode;
  int o = tid / KFEAT;
  float rs = ws[WS_RSUM + o];
  rs = (rs == 0.f) ? 1.f : rs;
  float base;
  if (use_rbuf){
    float s0=0.f, s1=0.f, s2=0.f, s3=0.f;
    for (int j = 0; j < NSLAB; j += 4){
      s0 += partial[(size_t)(j  )*4608 + tid];
      s1 += partial[(size_t)(j+1)*4608 + tid];
      s2 += partial[(size_t)(j+2)*4608 + tid];
      s3 += partial[(size_t)(j+3)*4608 + tid];
    }
    base = ((s0+s1)+(s2+s3)) / rs;
  } else {
    base = ws[WS_ACC + tid];   // fallback atomics (already /rsum)
  }
  float crsum = ws[WS_R2 + o] / rs;
  float wv = fp32 ? ((const float*)w)[tid] : bf2f(w[tid]);
  float d = base - crsum * wv;
  if (fp32) ((float*)dout)[(size_t)YELEMS + tid] = d;
  else      ((ushort_t*)dout)[(size_t)YELEMS + tid] = f2bf(d);
}

extern "C" void kernel_launch(void* const* d_in, const int* in_sizes, int n_in,
                              void* d_out, int out_size, void* d_ws, size_t ws_size,
                              hipStream_t stream){
  const void* x    = d_in[0];
  const ushort_t* w = (const ushort_t*)d_in[1];
  const void* bias = d_in[2];
  float* ws   = (float*)d_ws;
  int*   mode = (int*)(ws + WS_MODE);
  float* part = ws + WS_PART;
  ushort_t* sbuf = (ushort_t*)(ws + WS_SBUF);
  int use_rbuf = (ws_size >= WS_NEED) ? 1 : 0;

  hebb_detect<<<1, 256, 0, stream>>>((const ushort_t*)x, mode);
  hebb_prep<<<1, 256, 0, stream>>>(w, mode, ws);
  hebb_passA2<0><<<GRIDA, 256, 0, stream>>>(x, bias, mode, ws, sbuf,
                                            ws + WS_RSUM, ws + WS_R2, d_out, use_rbuf);
  hebb_passA2<1><<<GRIDA, 256, 0, stream>>>(x, bias, mode, ws, sbuf,
                                            ws + WS_RSUM, ws + WS_R2, d_out, use_rbuf);
  if (use_rbuf){
    hebb_passB2<0><<<GRIDB, 256, 0, stream>>>(x, mode, sbuf, part);
    hebb_passB2<1><<<GRIDB, 256, 0, stream>>>(x, mode, sbuf, part);
  } else {
    hebb_passB_fb<0><<<512, 256, 0, stream>>>(x, mode, ws, d_out, ws + WS_ACC);
    hebb_passB_fb<1><<<512, 256, 0, stream>>>(x, mode, ws, d_out, ws + WS_ACC);
  }
  hebb_fin<<<18, 256, 0, stream>>>(w, mode, ws, part, use_rbuf, d_out);
}